// Round 17
// baseline (374.308 us; speedup 1.0000x reference)
//
#include <hip/hip_runtime.h>
#include <stdint.h>

#define BATCH 32768
#define TT    25

typedef float f32x4 __attribute__((ext_vector_type(4)));
typedef short s16x8 __attribute__((ext_vector_type(8)));

// fc1w|fc2w|fc3w concatenated, bf16, row-major [384][1600]
__device__ __align__(16) short g_Wc[384 * 1600];

#define LOG2E 1.442695040888963f

__device__ __forceinline__ uint32_t f2bf(float v){
  uint32_t u = __float_as_uint(v);
  return (u + 0x7fffu + ((u >> 16) & 1u)) >> 16;   // RNE
}
__device__ __forceinline__ short f2bfs(float v){ return (short)f2bf(v); }

// packed f32x2 -> bf16x2 (RNE) via asm. ONLY in fc kernel: in the lstm kernel
// the "v"-constrained asm pushed arch VGPR 128->140 (R6), crossing the register
// quantum (128+64agpr=192 -> 2 waves/SIMD resident; more arch VGPR -> 1).
__device__ __forceinline__ uint32_t cvt_pk_bf16(float lo, float hi){
  uint32_t d;
  asm("v_cvt_pk_bf16_f32 %0, %1, %2" : "=v"(d) : "v"(lo), "v"(hi));
  return d;
}

__device__ __forceinline__ float sigm(float x){
  float e = __builtin_amdgcn_exp2f(-LOG2E * x);
  return __builtin_amdgcn_rcpf(1.0f + e);
}
__device__ __forceinline__ float tanh_(float x){
  float e = __builtin_amdgcn_exp2f(-2.0f*LOG2E * x);
  return 2.0f*__builtin_amdgcn_rcpf(1.0f + e) - 1.0f;
}
// bit-twiddle pack (proven regalloc: fits the lstm kernel at 128 arch VGPR)
__device__ __forceinline__ s16x8 pack8(float4 a, float4 b){
  s16x8 v;
  v[0]=f2bfs(a.x); v[1]=f2bfs(a.y); v[2]=f2bfs(a.z); v[3]=f2bfs(a.w);
  v[4]=f2bfs(b.x); v[5]=f2bfs(b.y); v[6]=f2bfs(b.z); v[7]=f2bfs(b.w);
  return v;
}

// Barrier that waits ONLY on LDS traffic (lgkmcnt), not on outstanding global
// stores (vmcnt). __syncthreads() emits s_waitcnt vmcnt(0) lgkmcnt(0) before
// s_barrier, which drains the fire-and-forget `flat` stores through HBM every
// timestep (~300-600cyc, m97 mechanism). Our only cross-wave dependency at the
// barrier is LDS. No register operands -> no regalloc perturbation.
__device__ __forceinline__ void barrier_lds_only(){
  asm volatile("s_waitcnt lgkmcnt(0)\n\ts_barrier" ::: "memory");
}

// ---------------- prologue: convert FC weights to bf16 ----------------
__global__ void conv_wc_kernel(const float* __restrict__ fc1w,
                               const float* __restrict__ fc2w,
                               const float* __restrict__ fc3w){
  const int j = blockIdx.x;
  const float* src = (j < 128) ? fc1w + j*1600
                   : (j < 256) ? fc2w + (j-128)*1600
                               : fc3w + (j-256)*1600;
  for (int k = threadIdx.x; k < 1600; k += 256)
    g_Wc[j*1600 + k] = f2bfs(src[k]);
}

// ---------------- Kernel 1: LSTM via MFMA (R11 + lgkm-only barrier) ----------
// 512 blocks x 512 threads (8 waves), 64 samples/block, VGPR=128(+64 AGPR) ->
// 8 waves/CU (2/SIMD), the register-quantum optimum (11 probes of the
// occupancy wall all regressed: R6/R7/R9/R10/R13/R14/R15). Structure:
// ALL weights in per-wave register B-fragments; LDS = only the h exchange,
// double-buffered (32KB); SINGLE barrier per timestep, now LGKM-ONLY (the
// vmcnt(0) drain of the flat stores was pure waste -- see barrier_lds_only).
__global__ __launch_bounds__(512, 1) void lstm2_mfma_kernel(
    const float* __restrict__ x,
    const float* __restrict__ wih0, const float* __restrict__ whh0,
    const float* __restrict__ bih0, const float* __restrict__ bhh0,
    const float* __restrict__ wih1, const float* __restrict__ whh1,
    const float* __restrict__ bih1, const float* __restrict__ bhh1,
    short* __restrict__ flat)                 // [BATCH][1600] bf16
{
  __shared__ short Abuf[4*64*64];   // 32 KiB: h0[0],h0[1],h1[0],h1[1]; [64s][64u] each
  char* const Ab = (char*)Abuf;     // region r at byte r*8192; row=128B, XOR-swizzled

  const int tid  = threadIdx.x;
  const int lane = tid & 63;
  const int wv   = tid >> 6;
  const int w4   = wv & 3;          // unit group
  const int wg   = wv >> 2;         // sample half
  const int lrow = lane & 15;
  const int lk   = lane >> 4;
  const int sw   = (lrow & 7) << 4;
  const int sb   = blockIdx.x * 64;
  const int u    = w4*16 + lrow;

  // ---- zero h0buf[1], h1buf[1] (read at t=0) ----
  {
    s16x8 z = {0,0,0,0,0,0,0,0};
    int idx = tid * 32;
    char* pz = Ab + ((idx < 8192) ? 8192 + idx : 16384 + idx);
    *(s16x8*)pz = z; *(s16x8*)(pz + 16) = z;
  }

  // ---- ALL weights as register B-fragments ----
  s16x8 W1f[4][4], B0x[4], B0h[4][2];
  #pragma unroll
  for (int n = 0; n < 4; n++){
    const int g = n*64 + u;                       // gate n, unit u
    #pragma unroll
    for (int kt = 0; kt < 4; kt++){
      const float* src = (kt < 2 ? wih1 + g*64 + kt*32 : whh1 + g*64 + (kt-2)*32) + lk*8;
      W1f[n][kt] = pack8(*(const float4*)src, *(const float4*)(src+4));
    }
    if (lk < 2){
      const float* src = wih0 + g*16 + lk*8;
      B0x[n] = pack8(*(const float4*)src, *(const float4*)(src+4));
    } else {
      s16x8 z = {0,0,0,0,0,0,0,0}; B0x[n] = z;
    }
    #pragma unroll
    for (int kt = 0; kt < 2; kt++){
      const float* src = whh0 + g*64 + kt*32 + lk*8;
      B0h[n][kt] = pack8(*(const float4*)src, *(const float4*)(src+4));
    }
  }

  // ---- biases (i,f,g,o for unit u) ----
  float b0v[4], b1v[4];
  #pragma unroll
  for (int n = 0; n < 4; n++){
    b0v[n] = bih0[n*64+u] + bhh0[n*64+u];
    b1v[n] = bih1[n*64+u] + bhh1[n*64+u];
  }

  // ---- x fragment pointers + t=0 prefetch ----
  const float* xbase[2];
  #pragma unroll
  for (int m = 0; m < 2; m++)
    xbase[m] = x + (size_t)(sb + wg*32 + m*16 + lrow)*(TT*16) + (lk&1)*8;
  s16x8 xf[2];
  #pragma unroll
  for (int m = 0; m < 2; m++)
    xf[m] = pack8(*(const float4*)(xbase[m]), *(const float4*)(xbase[m] + 4));

  float c0[2][4], c1[2][4];
  #pragma unroll
  for (int m = 0; m < 2; m++)
    #pragma unroll
    for (int r = 0; r < 4; r++){ c0[m][r] = 0.f; c1[m][r] = 0.f; }

  __syncthreads();   // one-time full barrier after staging

  #pragma unroll 1
  for (int t = 0; t < TT; t++){
    const int p  = t & 1;
    const int pn = p ^ 1;
    // ======== layer 0: x-tile (regs) + 2 h0-tiles from h0buf[pn] ========
    f32x4 acc[2][4];
    #pragma unroll
    for (int m = 0; m < 2; m++)
      #pragma unroll
      for (int n = 0; n < 4; n++){ f32x4 iv = {b0v[n],b0v[n],b0v[n],b0v[n]}; acc[m][n] = iv; }
    #pragma unroll
    for (int m = 0; m < 2; m++)
      #pragma unroll
      for (int n = 0; n < 4; n++)
        acc[m][n] = __builtin_amdgcn_mfma_f32_16x16x32_bf16(xf[m], B0x[n], acc[m][n], 0, 0, 0);
    #pragma unroll
    for (int kt = 0; kt < 2; kt++){
      s16x8 a[2];
      #pragma unroll
      for (int m = 0; m < 2; m++){
        int row = wg*32 + m*16 + lrow;
        a[m] = *(const s16x8*)(Ab + pn*8192 + row*128 + ((kt*64 + lk*16) ^ sw));
      }
      #pragma unroll
      for (int m = 0; m < 2; m++)
        #pragma unroll
        for (int n = 0; n < 4; n++)
          acc[m][n] = __builtin_amdgcn_mfma_f32_16x16x32_bf16(a[m], B0h[n][kt], acc[m][n], 0, 0, 0);
    }
    short hb[2][4];
    #pragma unroll
    for (int m = 0; m < 2; m++)
      #pragma unroll
      for (int r = 0; r < 4; r++){
        float iv = sigm(acc[m][0][r]);
        float fv = sigm(acc[m][1][r]);
        float gv = tanh_(acc[m][2][r]);
        float ov = sigm(acc[m][3][r]);
        float c  = fmaf(fv, c0[m][r], iv*gv); c0[m][r] = c;
        hb[m][r] = f2bfs(ov * tanh_(c));
      }
    // write h0[t] to h0buf[p] (disjoint from h0buf[pn] being read)
    #pragma unroll
    for (int m = 0; m < 2; m++)
      #pragma unroll
      for (int r = 0; r < 4; r++){
        int mine = (int)(uint16_t)hb[m][r];
        int part = __shfl_xor(mine, 1);
        if ((lane & 1) == 0){
          int s_ = wg*32 + m*16 + lk*4 + r;
          uint32_t pk = (uint32_t)mine | ((uint32_t)part << 16);
          *(uint32_t*)(Ab + p*8192 + s_*128 + ((u*2) ^ ((s_&7)<<4))) = pk;
        }
      }
    barrier_lds_only();   // S1 (the ONLY barrier): h0[t] and h1[t-1] visible

    // ======== layer 1: reads h0buf[p] (kt 0,1) + h1buf[pn] (kt 2,3) ========
    // Hazards without an end-of-phase barrier (double-buffered regions):
    //   h1[t] write -> read L1[t+1]: next phase's S1 between.     RAW ok
    //   h0buf[pn] read (pre-S1_t) -> rewritten after S1_{t+1}.    WAR ok
    //   h1buf[pn] read (post-S1_t) -> rewritten after S1_{t+1}.   WAR ok
    s16x8 xfn[2];
    if (t + 1 < TT){
      #pragma unroll
      for (int m = 0; m < 2; m++)
        xfn[m] = pack8(*(const float4*)(xbase[m] + (t+1)*16),
                       *(const float4*)(xbase[m] + (t+1)*16 + 4));
    }
    #pragma unroll
    for (int m = 0; m < 2; m++)
      #pragma unroll
      for (int n = 0; n < 4; n++){ f32x4 iv = {b1v[n],b1v[n],b1v[n],b1v[n]}; acc[m][n] = iv; }
    #pragma unroll
    for (int kt = 0; kt < 4; kt++){
      const int reg = (kt < 2) ? p*8192 : 16384 + pn*8192;
      const int ko  = (kt & 1) * 64;
      s16x8 a[2];
      #pragma unroll
      for (int m = 0; m < 2; m++){
        int row = wg*32 + m*16 + lrow;
        a[m] = *(const s16x8*)(Ab + reg + row*128 + ((ko + lk*16) ^ sw));
      }
      #pragma unroll
      for (int m = 0; m < 2; m++)
        #pragma unroll
        for (int n = 0; n < 4; n++)
          acc[m][n] = __builtin_amdgcn_mfma_f32_16x16x32_bf16(a[m], W1f[n][kt], acc[m][n], 0, 0, 0);
    }
    #pragma unroll
    for (int m = 0; m < 2; m++)
      #pragma unroll
      for (int r = 0; r < 4; r++){
        float iv = sigm(acc[m][0][r]);
        float fv = sigm(acc[m][1][r]);
        float gv = tanh_(acc[m][2][r]);
        float ov = sigm(acc[m][3][r]);
        float c  = fmaf(fv, c1[m][r], iv*gv); c1[m][r] = c;
        hb[m][r] = f2bfs(ov * tanh_(c));
      }
    // write h1[t] to h1buf[p] + flat. Visible to L1[t+1] via next phase's S1.
    // The flat global stores are fire-and-forget: the lgkm-only barrier does
    // NOT drain them; kernel completion fences them before fc reads flat.
    #pragma unroll
    for (int m = 0; m < 2; m++)
      #pragma unroll
      for (int r = 0; r < 4; r++){
        int mine = (int)(uint16_t)hb[m][r];
        int part = __shfl_xor(mine, 1);
        if ((lane & 1) == 0){
          int s_ = wg*32 + m*16 + lk*4 + r;
          uint32_t pk = (uint32_t)mine | ((uint32_t)part << 16);
          *(uint32_t*)(Ab + 16384 + p*8192 + s_*128 + ((u*2) ^ ((s_&7)<<4))) = pk;
          *(uint32_t*)(flat + (size_t)(sb+s_)*1600 + t*64 + u) = pk;
        }
      }
    #pragma unroll
    for (int m = 0; m < 2; m++) xf[m] = xfn[m];
    // no end-of-phase barrier: next phase's S1 covers all hazards (see above)
  }
}

// ---------------- Kernel 2: FC GEMM + MFMA heads (R11 version, best: ~77us) --
// 512 blocks x 256 threads (4 waves, 64 samples). R bf16 in swizzled LDS
// (48KB); heads via 3 padded-N MFMA tiles. R12 dbuf neutral, R13 8-wave split
// regressed -- this is the best measured fc.
__global__ __launch_bounds__(256,1) void fc_mfma_kernel(
    const short* __restrict__ flat,
    const float* __restrict__ fc1b, const float* __restrict__ fc2b, const float* __restrict__ fc3b,
    const float* __restrict__ l1w,  const float* __restrict__ l1b,
    const float* __restrict__ l2w,  const float* __restrict__ l2b,
    const float* __restrict__ l3w,  const float* __restrict__ l3b,
    float* __restrict__ out)
{
  __shared__ short Rs[64*384];    // 48KB bf16, row=768B, XOR-swizzled
  char* const Rb = (char*)Rs;
  const int tid  = threadIdx.x;
  const int lane = tid & 63;
  const int wv   = tid >> 6;      // wave owns fc cols [96w, 96w+96)
  const int lrow = lane & 15;
  const int lk   = lane >> 4;
  const int sb   = blockIdx.x * 64;

  f32x4 acc[4][6];
  #pragma unroll
  for (int n = 0; n < 6; n++){
    int j = wv*96 + n*16 + lrow;
    float bv = (j < 128) ? fc1b[j] : (j < 256) ? fc2b[j-128] : fc3b[j-256];
    #pragma unroll
    for (int m = 0; m < 4; m++){ f32x4 iv = {bv,bv,bv,bv}; acc[m][n] = iv; }
  }

  const char* Abase = (const char*)(flat + (size_t)sb*1600);
  const char* Bbase = (const char*)g_Wc;
  #pragma unroll 1
  for (int kc = 0; kc < 50; kc++){
    s16x8 a[4], b[6];
    #pragma unroll
    for (int m = 0; m < 4; m++)
      a[m] = *(const s16x8*)(Abase + (size_t)(m*16+lrow)*3200 + kc*64 + lk*16);
    #pragma unroll
    for (int n = 0; n < 6; n++)
      b[n] = *(const s16x8*)(Bbase + (size_t)(wv*96+n*16+lrow)*3200 + kc*64 + lk*16);
    #pragma unroll
    for (int m = 0; m < 4; m++)
      #pragma unroll
      for (int n = 0; n < 6; n++)
        acc[m][n] = __builtin_amdgcn_mfma_f32_16x16x32_bf16(a[m], b[n], acc[m][n], 0, 0, 0);
  }

  // ---- ReLU + write R as bf16 pairs (pairs across lrow/lrow^1 lanes) ----
  #pragma unroll
  for (int m = 0; m < 4; m++)
    #pragma unroll
    for (int n = 0; n < 6; n++)
      #pragma unroll
      for (int r = 0; r < 4; r++){
        float v  = fmaxf(acc[m][n][r], 0.f);
        float vp = __shfl_xor(v, 1);
        uint32_t pk = cvt_pk_bf16(v, vp);
        if ((lane & 1) == 0){
          int s_ = m*16 + lk*4 + r;
          int fc = wv*96 + n*16 + lrow;
          *(uint32_t*)(Rb + s_*768 + ((fc*2) ^ ((s_&7)<<4))) = pk;
        }
      }
  __syncthreads();

  // ---- heads as 3 padded-N MFMA tiles (K=128 each) ----
  const float* Lw[3] = {l1w, l2w, l3w};
  const int   odim[3] = {5, 4, 8};
  s16x8 Bh[3][4];
  #pragma unroll
  for (int q = 0; q < 3; q++){
    #pragma unroll
    for (int kt = 0; kt < 4; kt++){
      if (lrow < odim[q]){
        const float* src = Lw[q] + lrow*128 + kt*32 + lk*8;
        Bh[q][kt] = pack8(*(const float4*)src, *(const float4*)(src+4));
      } else {
        s16x8 z = {0,0,0,0,0,0,0,0}; Bh[q][kt] = z;
      }
    }
  }
  f32x4 acc2[4][3];
  {
    float bv0 = (lrow < 5) ? l1b[lrow] : 0.f;
    float bv1 = (lrow < 4) ? l2b[lrow] : 0.f;
    float bv2 = (lrow < 8) ? l3b[lrow] : 0.f;
    #pragma unroll
    for (int m = 0; m < 4; m++){
      f32x4 i0 = {bv0,bv0,bv0,bv0}; acc2[m][0] = i0;
      f32x4 i1 = {bv1,bv1,bv1,bv1}; acc2[m][1] = i1;
      f32x4 i2 = {bv2,bv2,bv2,bv2}; acc2[m][2] = i2;
    }
  }
  #pragma unroll
  for (int q = 0; q < 3; q++){
    #pragma unroll
    for (int kt = 0; kt < 4; kt++){
      s16x8 av[4];
      #pragma unroll
      for (int m = 0; m < 4; m++){
        int row = m*16 + lrow;
        av[m] = *(const s16x8*)(Rb + row*768 + ((q*256 + kt*64 + lk*16) ^ ((row&7)<<4)));
      }
      #pragma unroll
      for (int m = 0; m < 4; m++)
        acc2[m][q] = __builtin_amdgcn_mfma_f32_16x16x32_bf16(av[m], Bh[q][kt], acc2[m][q], 0, 0, 0);
    }
  }
  #pragma unroll
  for (int m = 0; m < 4; m++)
    #pragma unroll
    for (int r = 0; r < 4; r++){
      int smp = sb + m*16 + lk*4 + r;
      if (lrow < 5) out[(size_t)smp*5 + lrow] = acc2[m][0][r];
      if (lrow < 4) out[(size_t)BATCH*5 + (size_t)smp*4 + lrow] = acc2[m][1][r];
      if (lrow < 8) out[(size_t)BATCH*9 + (size_t)smp*8 + lrow] = acc2[m][2][r];
    }
}

extern "C" void kernel_launch(void* const* d_in, const int* in_sizes, int n_in,
                              void* d_out, int out_size, void* d_ws, size_t ws_size,
                              hipStream_t stream)
{
  const float* x    = (const float*)d_in[0];
  const float* wih0 = (const float*)d_in[1];
  const float* whh0 = (const float*)d_in[2];
  const float* bih0 = (const float*)d_in[3];
  const float* bhh0 = (const float*)d_in[4];
  const float* wih1 = (const float*)d_in[5];
  const float* whh1 = (const float*)d_in[6];
  const float* bih1 = (const float*)d_in[7];
  const float* bhh1 = (const float*)d_in[8];
  const float* fc1w = (const float*)d_in[9];
  const float* fc1b = (const float*)d_in[10];
  const float* fc2w = (const float*)d_in[11];
  const float* fc2b = (const float*)d_in[12];
  const float* fc3w = (const float*)d_in[13];
  const float* fc3b = (const float*)d_in[14];
  const float* l1w  = (const float*)d_in[15];
  const float* l1b  = (const float*)d_in[16];
  const float* l2w  = (const float*)d_in[17];
  const float* l2b  = (const float*)d_in[18];
  const float* l3w  = (const float*)d_in[19];
  const float* l3b  = (const float*)d_in[20];

  float* out  = (float*)d_out;
  short* flat = (short*)d_ws;
  if (ws_size < (size_t)BATCH*1600*2) return;

  conv_wc_kernel<<<dim3(384), dim3(256), 0, stream>>>(fc1w, fc2w, fc3w);

  lstm2_mfma_kernel<<<dim3(BATCH/64), dim3(512), 0, stream>>>(
      x, wih0, whh0, bih0, bhh0, wih1, whh1, bih1, bhh1, flat);

  fc_mfma_kernel<<<dim3(BATCH/64), dim3(256), 0, stream>>>(
      flat, fc1b, fc2b, fc3b, l1w, l1b, l2w, l2b, l3w, l3b, out);
}

// Round 18
// 363.871 us; speedup vs baseline: 1.0287x; 1.0287x over previous
//
#include <hip/hip_runtime.h>
#include <stdint.h>

#define BATCH 32768
#define TT    25

typedef float f32x4 __attribute__((ext_vector_type(4)));
typedef short s16x8 __attribute__((ext_vector_type(8)));

// fc1w|fc2w|fc3w concatenated, bf16, row-major [384][1600]
__device__ __align__(16) short g_Wc[384 * 1600];

#define LOG2E 1.442695040888963f

__device__ __forceinline__ uint32_t f2bf(float v){
  uint32_t u = __float_as_uint(v);
  return (u + 0x7fffu + ((u >> 16) & 1u)) >> 16;   // RNE
}
__device__ __forceinline__ short f2bfs(float v){ return (short)f2bf(v); }

// packed f32x2 -> bf16x2 (RNE) via asm. ONLY in fc kernel: in the lstm kernel
// the "v"-constrained asm pushed arch VGPR 128->140 (R6), crossing the register
// quantum (128+64agpr=192 -> 2 waves/SIMD resident; more arch VGPR -> 1).
__device__ __forceinline__ uint32_t cvt_pk_bf16(float lo, float hi){
  uint32_t d;
  asm("v_cvt_pk_bf16_f32 %0, %1, %2" : "=v"(d) : "v"(lo), "v"(hi));
  return d;
}

// lane^1 exchange via DPP quad_perm [1,0,3,2] -- guaranteed 1 VALU op.
// R18 hypothesis: __shfl_xor(v,1) may lower to ds_swizzle/bpermute (LDS pipe,
// ~120cyc latency, m117); 16 of these per wave per timestep feeding dependent
// pack->ds_write chains would explain a chunk of the unattributed stall.
// mov_dpp has no operand constraints -> no regalloc perturbation.
__device__ __forceinline__ int dpp_swap1(int v){
  return __builtin_amdgcn_mov_dpp(v, 0xB1, 0xF, 0xF, true);
}

__device__ __forceinline__ float sigm(float x){
  float e = __builtin_amdgcn_exp2f(-LOG2E * x);
  return __builtin_amdgcn_rcpf(1.0f + e);
}
__device__ __forceinline__ float tanh_(float x){
  float e = __builtin_amdgcn_exp2f(-2.0f*LOG2E * x);
  return 2.0f*__builtin_amdgcn_rcpf(1.0f + e) - 1.0f;
}
// bit-twiddle pack (proven regalloc: fits the lstm kernel at 128 arch VGPR)
__device__ __forceinline__ s16x8 pack8(float4 a, float4 b){
  s16x8 v;
  v[0]=f2bfs(a.x); v[1]=f2bfs(a.y); v[2]=f2bfs(a.z); v[3]=f2bfs(a.w);
  v[4]=f2bfs(b.x); v[5]=f2bfs(b.y); v[6]=f2bfs(b.z); v[7]=f2bfs(b.w);
  return v;
}

// Barrier that waits ONLY on LDS traffic (lgkmcnt), not outstanding global
// stores (vmcnt). R17: neutral vs __syncthreads, kept for theoretical cleanliness.
__device__ __forceinline__ void barrier_lds_only(){
  asm volatile("s_waitcnt lgkmcnt(0)\n\ts_barrier" ::: "memory");
}

// ---------------- prologue: convert FC weights to bf16 ----------------
__global__ void conv_wc_kernel(const float* __restrict__ fc1w,
                               const float* __restrict__ fc2w,
                               const float* __restrict__ fc3w){
  const int j = blockIdx.x;
  const float* src = (j < 128) ? fc1w + j*1600
                   : (j < 256) ? fc2w + (j-128)*1600
                               : fc3w + (j-256)*1600;
  for (int k = threadIdx.x; k < 1600; k += 256)
    g_Wc[j*1600 + k] = f2bfs(src[k]);
}

// ---------------- Kernel 1: LSTM via MFMA (R17 + DPP lane exchange) ----------
// 512 blocks x 512 threads (8 waves), 64 samples/block, VGPR=128(+64 AGPR) ->
// 1 block/CU resident (2 waves/SIMD), the register-file optimum (R14 model;
// 11 occupancy probes all regressed). ALL weights in per-wave register
// B-fragments; LDS = only the h exchange, double-buffered (32KB); single
// lgkm-only barrier per timestep. CHANGE vs R17: __shfl_xor -> mov_dpp.
__global__ __launch_bounds__(512, 1) void lstm2_mfma_kernel(
    const float* __restrict__ x,
    const float* __restrict__ wih0, const float* __restrict__ whh0,
    const float* __restrict__ bih0, const float* __restrict__ bhh0,
    const float* __restrict__ wih1, const float* __restrict__ whh1,
    const float* __restrict__ bih1, const float* __restrict__ bhh1,
    short* __restrict__ flat)                 // [BATCH][1600] bf16
{
  __shared__ short Abuf[4*64*64];   // 32 KiB: h0[0],h0[1],h1[0],h1[1]; [64s][64u] each
  char* const Ab = (char*)Abuf;     // region r at byte r*8192; row=128B, XOR-swizzled

  const int tid  = threadIdx.x;
  const int lane = tid & 63;
  const int wv   = tid >> 6;
  const int w4   = wv & 3;          // unit group
  const int wg   = wv >> 2;         // sample half
  const int lrow = lane & 15;
  const int lk   = lane >> 4;
  const int sw   = (lrow & 7) << 4;
  const int sb   = blockIdx.x * 64;
  const int u    = w4*16 + lrow;

  // ---- zero h0buf[1], h1buf[1] (read at t=0) ----
  {
    s16x8 z = {0,0,0,0,0,0,0,0};
    int idx = tid * 32;
    char* pz = Ab + ((idx < 8192) ? 8192 + idx : 16384 + idx);
    *(s16x8*)pz = z; *(s16x8*)(pz + 16) = z;
  }

  // ---- ALL weights as register B-fragments ----
  s16x8 W1f[4][4], B0x[4], B0h[4][2];
  #pragma unroll
  for (int n = 0; n < 4; n++){
    const int g = n*64 + u;                       // gate n, unit u
    #pragma unroll
    for (int kt = 0; kt < 4; kt++){
      const float* src = (kt < 2 ? wih1 + g*64 + kt*32 : whh1 + g*64 + (kt-2)*32) + lk*8;
      W1f[n][kt] = pack8(*(const float4*)src, *(const float4*)(src+4));
    }
    if (lk < 2){
      const float* src = wih0 + g*16 + lk*8;
      B0x[n] = pack8(*(const float4*)src, *(const float4*)(src+4));
    } else {
      s16x8 z = {0,0,0,0,0,0,0,0}; B0x[n] = z;
    }
    #pragma unroll
    for (int kt = 0; kt < 2; kt++){
      const float* src = whh0 + g*64 + kt*32 + lk*8;
      B0h[n][kt] = pack8(*(const float4*)src, *(const float4*)(src+4));
    }
  }

  // ---- biases (i,f,g,o for unit u) ----
  float b0v[4], b1v[4];
  #pragma unroll
  for (int n = 0; n < 4; n++){
    b0v[n] = bih0[n*64+u] + bhh0[n*64+u];
    b1v[n] = bih1[n*64+u] + bhh1[n*64+u];
  }

  // ---- x fragment pointers + t=0 prefetch ----
  const float* xbase[2];
  #pragma unroll
  for (int m = 0; m < 2; m++)
    xbase[m] = x + (size_t)(sb + wg*32 + m*16 + lrow)*(TT*16) + (lk&1)*8;
  s16x8 xf[2];
  #pragma unroll
  for (int m = 0; m < 2; m++)
    xf[m] = pack8(*(const float4*)(xbase[m]), *(const float4*)(xbase[m] + 4));

  float c0[2][4], c1[2][4];
  #pragma unroll
  for (int m = 0; m < 2; m++)
    #pragma unroll
    for (int r = 0; r < 4; r++){ c0[m][r] = 0.f; c1[m][r] = 0.f; }

  __syncthreads();   // one-time full barrier after staging

  #pragma unroll 1
  for (int t = 0; t < TT; t++){
    const int p  = t & 1;
    const int pn = p ^ 1;
    // ======== layer 0: x-tile (regs) + 2 h0-tiles from h0buf[pn] ========
    f32x4 acc[2][4];
    #pragma unroll
    for (int m = 0; m < 2; m++)
      #pragma unroll
      for (int n = 0; n < 4; n++){ f32x4 iv = {b0v[n],b0v[n],b0v[n],b0v[n]}; acc[m][n] = iv; }
    #pragma unroll
    for (int m = 0; m < 2; m++)
      #pragma unroll
      for (int n = 0; n < 4; n++)
        acc[m][n] = __builtin_amdgcn_mfma_f32_16x16x32_bf16(xf[m], B0x[n], acc[m][n], 0, 0, 0);
    #pragma unroll
    for (int kt = 0; kt < 2; kt++){
      s16x8 a[2];
      #pragma unroll
      for (int m = 0; m < 2; m++){
        int row = wg*32 + m*16 + lrow;
        a[m] = *(const s16x8*)(Ab + pn*8192 + row*128 + ((kt*64 + lk*16) ^ sw));
      }
      #pragma unroll
      for (int m = 0; m < 2; m++)
        #pragma unroll
        for (int n = 0; n < 4; n++)
          acc[m][n] = __builtin_amdgcn_mfma_f32_16x16x32_bf16(a[m], B0h[n][kt], acc[m][n], 0, 0, 0);
    }
    short hb[2][4];
    #pragma unroll
    for (int m = 0; m < 2; m++)
      #pragma unroll
      for (int r = 0; r < 4; r++){
        float iv = sigm(acc[m][0][r]);
        float fv = sigm(acc[m][1][r]);
        float gv = tanh_(acc[m][2][r]);
        float ov = sigm(acc[m][3][r]);
        float c  = fmaf(fv, c0[m][r], iv*gv); c0[m][r] = c;
        hb[m][r] = f2bfs(ov * tanh_(c));
      }
    // write h0[t] to h0buf[p] (disjoint from h0buf[pn] being read)
    #pragma unroll
    for (int m = 0; m < 2; m++)
      #pragma unroll
      for (int r = 0; r < 4; r++){
        int mine = (int)(uint16_t)hb[m][r];
        int part = dpp_swap1(mine);
        if ((lane & 1) == 0){
          int s_ = wg*32 + m*16 + lk*4 + r;
          uint32_t pk = (uint32_t)mine | ((uint32_t)part << 16);
          *(uint32_t*)(Ab + p*8192 + s_*128 + ((u*2) ^ ((s_&7)<<4))) = pk;
        }
      }
    barrier_lds_only();   // S1 (the ONLY barrier): h0[t] and h1[t-1] visible

    // ======== layer 1: reads h0buf[p] (kt 0,1) + h1buf[pn] (kt 2,3) ========
    // Hazards without an end-of-phase barrier (double-buffered regions):
    //   h1[t] write -> read L1[t+1]: next phase's S1 between.     RAW ok
    //   h0buf[pn] read (pre-S1_t) -> rewritten after S1_{t+1}.    WAR ok
    //   h1buf[pn] read (post-S1_t) -> rewritten after S1_{t+1}.   WAR ok
    s16x8 xfn[2];
    if (t + 1 < TT){
      #pragma unroll
      for (int m = 0; m < 2; m++)
        xfn[m] = pack8(*(const float4*)(xbase[m] + (t+1)*16),
                       *(const float4*)(xbase[m] + (t+1)*16 + 4));
    }
    #pragma unroll
    for (int m = 0; m < 2; m++)
      #pragma unroll
      for (int n = 0; n < 4; n++){ f32x4 iv = {b1v[n],b1v[n],b1v[n],b1v[n]}; acc[m][n] = iv; }
    #pragma unroll
    for (int kt = 0; kt < 4; kt++){
      const int reg = (kt < 2) ? p*8192 : 16384 + pn*8192;
      const int ko  = (kt & 1) * 64;
      s16x8 a[2];
      #pragma unroll
      for (int m = 0; m < 2; m++){
        int row = wg*32 + m*16 + lrow;
        a[m] = *(const s16x8*)(Ab + reg + row*128 + ((ko + lk*16) ^ sw));
      }
      #pragma unroll
      for (int m = 0; m < 2; m++)
        #pragma unroll
        for (int n = 0; n < 4; n++)
          acc[m][n] = __builtin_amdgcn_mfma_f32_16x16x32_bf16(a[m], W1f[n][kt], acc[m][n], 0, 0, 0);
    }
    #pragma unroll
    for (int m = 0; m < 2; m++)
      #pragma unroll
      for (int r = 0; r < 4; r++){
        float iv = sigm(acc[m][0][r]);
        float fv = sigm(acc[m][1][r]);
        float gv = tanh_(acc[m][2][r]);
        float ov = sigm(acc[m][3][r]);
        float c  = fmaf(fv, c1[m][r], iv*gv); c1[m][r] = c;
        hb[m][r] = f2bfs(ov * tanh_(c));
      }
    // write h1[t] to h1buf[p] + flat. Visible to L1[t+1] via next phase's S1.
    // flat stores are fire-and-forget; kernel completion fences them for fc.
    #pragma unroll
    for (int m = 0; m < 2; m++)
      #pragma unroll
      for (int r = 0; r < 4; r++){
        int mine = (int)(uint16_t)hb[m][r];
        int part = dpp_swap1(mine);
        if ((lane & 1) == 0){
          int s_ = wg*32 + m*16 + lk*4 + r;
          uint32_t pk = (uint32_t)mine | ((uint32_t)part << 16);
          *(uint32_t*)(Ab + 16384 + p*8192 + s_*128 + ((u*2) ^ ((s_&7)<<4))) = pk;
          *(uint32_t*)(flat + (size_t)(sb+s_)*1600 + t*64 + u) = pk;
        }
      }
    #pragma unroll
    for (int m = 0; m < 2; m++) xf[m] = xfn[m];
    // no end-of-phase barrier: next phase's S1 covers all hazards (see above)
  }
}

// ---------------- Kernel 2: FC GEMM + MFMA heads (R11 version, best: ~77us) --
// 512 blocks x 256 threads (4 waves, 64 samples). R bf16 in swizzled LDS
// (48KB); heads via 3 padded-N MFMA tiles. R12 dbuf neutral, R13 8-wave split
// regressed -- this is the best measured fc.
__global__ __launch_bounds__(256,1) void fc_mfma_kernel(
    const short* __restrict__ flat,
    const float* __restrict__ fc1b, const float* __restrict__ fc2b, const float* __restrict__ fc3b,
    const float* __restrict__ l1w,  const float* __restrict__ l1b,
    const float* __restrict__ l2w,  const float* __restrict__ l2b,
    const float* __restrict__ l3w,  const float* __restrict__ l3b,
    float* __restrict__ out)
{
  __shared__ short Rs[64*384];    // 48KB bf16, row=768B, XOR-swizzled
  char* const Rb = (char*)Rs;
  const int tid  = threadIdx.x;
  const int lane = tid & 63;
  const int wv   = tid >> 6;      // wave owns fc cols [96w, 96w+96)
  const int lrow = lane & 15;
  const int lk   = lane >> 4;
  const int sb   = blockIdx.x * 64;

  f32x4 acc[4][6];
  #pragma unroll
  for (int n = 0; n < 6; n++){
    int j = wv*96 + n*16 + lrow;
    float bv = (j < 128) ? fc1b[j] : (j < 256) ? fc2b[j-128] : fc3b[j-256];
    #pragma unroll
    for (int m = 0; m < 4; m++){ f32x4 iv = {bv,bv,bv,bv}; acc[m][n] = iv; }
  }

  const char* Abase = (const char*)(flat + (size_t)sb*1600);
  const char* Bbase = (const char*)g_Wc;
  #pragma unroll 1
  for (int kc = 0; kc < 50; kc++){
    s16x8 a[4], b[6];
    #pragma unroll
    for (int m = 0; m < 4; m++)
      a[m] = *(const s16x8*)(Abase + (size_t)(m*16+lrow)*3200 + kc*64 + lk*16);
    #pragma unroll
    for (int n = 0; n < 6; n++)
      b[n] = *(const s16x8*)(Bbase + (size_t)(wv*96+n*16+lrow)*3200 + kc*64 + lk*16);
    #pragma unroll
    for (int m = 0; m < 4; m++)
      #pragma unroll
      for (int n = 0; n < 6; n++)
        acc[m][n] = __builtin_amdgcn_mfma_f32_16x16x32_bf16(a[m], b[n], acc[m][n], 0, 0, 0);
  }

  // ---- ReLU + write R as bf16 pairs (pairs across lrow/lrow^1 lanes) ----
  #pragma unroll
  for (int m = 0; m < 4; m++)
    #pragma unroll
    for (int n = 0; n < 6; n++)
      #pragma unroll
      for (int r = 0; r < 4; r++){
        float v  = fmaxf(acc[m][n][r], 0.f);
        float vp = __shfl_xor(v, 1);
        uint32_t pk = cvt_pk_bf16(v, vp);
        if ((lane & 1) == 0){
          int s_ = m*16 + lk*4 + r;
          int fc = wv*96 + n*16 + lrow;
          *(uint32_t*)(Rb + s_*768 + ((fc*2) ^ ((s_&7)<<4))) = pk;
        }
      }
  __syncthreads();

  // ---- heads as 3 padded-N MFMA tiles (K=128 each) ----
  const float* Lw[3] = {l1w, l2w, l3w};
  const int   odim[3] = {5, 4, 8};
  s16x8 Bh[3][4];
  #pragma unroll
  for (int q = 0; q < 3; q++){
    #pragma unroll
    for (int kt = 0; kt < 4; kt++){
      if (lrow < odim[q]){
        const float* src = Lw[q] + lrow*128 + kt*32 + lk*8;
        Bh[q][kt] = pack8(*(const float4*)src, *(const float4*)(src+4));
      } else {
        s16x8 z = {0,0,0,0,0,0,0,0}; Bh[q][kt] = z;
      }
    }
  }
  f32x4 acc2[4][3];
  {
    float bv0 = (lrow < 5) ? l1b[lrow] : 0.f;
    float bv1 = (lrow < 4) ? l2b[lrow] : 0.f;
    float bv2 = (lrow < 8) ? l3b[lrow] : 0.f;
    #pragma unroll
    for (int m = 0; m < 4; m++){
      f32x4 i0 = {bv0,bv0,bv0,bv0}; acc2[m][0] = i0;
      f32x4 i1 = {bv1,bv1,bv1,bv1}; acc2[m][1] = i1;
      f32x4 i2 = {bv2,bv2,bv2,bv2}; acc2[m][2] = i2;
    }
  }
  #pragma unroll
  for (int q = 0; q < 3; q++){
    #pragma unroll
    for (int kt = 0; kt < 4; kt++){
      s16x8 av[4];
      #pragma unroll
      for (int m = 0; m < 4; m++){
        int row = m*16 + lrow;
        av[m] = *(const s16x8*)(Rb + row*768 + ((q*256 + kt*64 + lk*16) ^ ((row&7)<<4)));
      }
      #pragma unroll
      for (int m = 0; m < 4; m++)
        acc2[m][q] = __builtin_amdgcn_mfma_f32_16x16x32_bf16(av[m], Bh[q][kt], acc2[m][q], 0, 0, 0);
    }
  }
  #pragma unroll
  for (int m = 0; m < 4; m++)
    #pragma unroll
    for (int r = 0; r < 4; r++){
      int smp = sb + m*16 + lk*4 + r;
      if (lrow < 5) out[(size_t)smp*5 + lrow] = acc2[m][0][r];
      if (lrow < 4) out[(size_t)BATCH*5 + (size_t)smp*4 + lrow] = acc2[m][1][r];
      if (lrow < 8) out[(size_t)BATCH*9 + (size_t)smp*8 + lrow] = acc2[m][2][r];
    }
}

extern "C" void kernel_launch(void* const* d_in, const int* in_sizes, int n_in,
                              void* d_out, int out_size, void* d_ws, size_t ws_size,
                              hipStream_t stream)
{
  const float* x    = (const float*)d_in[0];
  const float* wih0 = (const float*)d_in[1];
  const float* whh0 = (const float*)d_in[2];
  const float* bih0 = (const float*)d_in[3];
  const float* bhh0 = (const float*)d_in[4];
  const float* wih1 = (const float*)d_in[5];
  const float* whh1 = (const float*)d_in[6];
  const float* bih1 = (const float*)d_in[7];
  const float* bhh1 = (const float*)d_in[8];
  const float* fc1w = (const float*)d_in[9];
  const float* fc1b = (const float*)d_in[10];
  const float* fc2w = (const float*)d_in[11];
  const float* fc2b = (const float*)d_in[12];
  const float* fc3w = (const float*)d_in[13];
  const float* fc3b = (const float*)d_in[14];
  const float* l1w  = (const float*)d_in[15];
  const float* l1b  = (const float*)d_in[16];
  const float* l2w  = (const float*)d_in[17];
  const float* l2b  = (const float*)d_in[18];
  const float* l3w  = (const float*)d_in[19];
  const float* l3b  = (const float*)d_in[20];

  float* out  = (float*)d_out;
  short* flat = (short*)d_ws;
  if (ws_size < (size_t)BATCH*1600*2) return;

  conv_wc_kernel<<<dim3(384), dim3(256), 0, stream>>>(fc1w, fc2w, fc3w);

  lstm2_mfma_kernel<<<dim3(BATCH/64), dim3(512), 0, stream>>>(
      x, wih0, whh0, bih0, bhh0, wih1, whh1, bih1, bhh1, flat);

  fc_mfma_kernel<<<dim3(BATCH/64), dim3(256), 0, stream>>>(
      flat, fc1b, fc2b, fc3b, l1w, l1b, l2w, l2b, l3w, l3b, out);
}

// Round 19
// 362.422 us; speedup vs baseline: 1.0328x; 1.0040x over previous
//
#include <hip/hip_runtime.h>
#include <stdint.h>

#define BATCH 32768
#define TT    25

typedef float f32x4 __attribute__((ext_vector_type(4)));
typedef short s16x8 __attribute__((ext_vector_type(8)));

// fc1w|fc2w|fc3w concatenated, bf16, row-major [384][1600]
__device__ __align__(16) short g_Wc[384 * 1600];

#define LOG2E 1.442695040888963f

__device__ __forceinline__ uint32_t f2bf(float v){
  uint32_t u = __float_as_uint(v);
  return (u + 0x7fffu + ((u >> 16) & 1u)) >> 16;   // RNE
}
__device__ __forceinline__ short f2bfs(float v){ return (short)f2bf(v); }

// packed f32x2 -> bf16x2 (RNE) via asm. ONLY in fc kernel: in the lstm kernel
// the "v"-constrained asm pushed arch VGPR 128->140 (R6), crossing the register
// quantum (128+64agpr=192 -> 2 waves/SIMD resident; more arch VGPR -> 1).
__device__ __forceinline__ uint32_t cvt_pk_bf16(float lo, float hi){
  uint32_t d;
  asm("v_cvt_pk_bf16_f32 %0, %1, %2" : "=v"(d) : "v"(lo), "v"(hi));
  return d;
}

// lane^1 exchange via DPP quad_perm [1,0,3,2] -- guaranteed 1 VALU op.
// R18 MEASURED: replacing __shfl_xor(v,1) with this in the lstm h-writes bought
// -12us (296->284): __shfl_xor lowers through the LDS pipe (~120cyc latency).
// No operand constraints -> no regalloc perturbation.
__device__ __forceinline__ int dpp_swap1(int v){
  return __builtin_amdgcn_mov_dpp(v, 0xB1, 0xF, 0xF, true);
}
__device__ __forceinline__ float dpp_swap1f(float v){
  return __int_as_float(__builtin_amdgcn_mov_dpp(__float_as_int(v), 0xB1, 0xF, 0xF, true));
}

__device__ __forceinline__ float sigm(float x){
  float e = __builtin_amdgcn_exp2f(-LOG2E * x);
  return __builtin_amdgcn_rcpf(1.0f + e);
}
__device__ __forceinline__ float tanh_(float x){
  float e = __builtin_amdgcn_exp2f(-2.0f*LOG2E * x);
  return 2.0f*__builtin_amdgcn_rcpf(1.0f + e) - 1.0f;
}
// bit-twiddle pack (proven regalloc: fits the lstm kernel at 128 arch VGPR)
__device__ __forceinline__ s16x8 pack8(float4 a, float4 b){
  s16x8 v;
  v[0]=f2bfs(a.x); v[1]=f2bfs(a.y); v[2]=f2bfs(a.z); v[3]=f2bfs(a.w);
  v[4]=f2bfs(b.x); v[5]=f2bfs(b.y); v[6]=f2bfs(b.z); v[7]=f2bfs(b.w);
  return v;
}

// Barrier that waits ONLY on LDS traffic (lgkmcnt), not outstanding global
// stores (vmcnt). R17: neutral vs __syncthreads, kept for theoretical cleanliness.
__device__ __forceinline__ void barrier_lds_only(){
  asm volatile("s_waitcnt lgkmcnt(0)\n\ts_barrier" ::: "memory");
}

// ---------------- prologue: convert FC weights to bf16 ----------------
__global__ void conv_wc_kernel(const float* __restrict__ fc1w,
                               const float* __restrict__ fc2w,
                               const float* __restrict__ fc3w){
  const int j = blockIdx.x;
  const float* src = (j < 128) ? fc1w + j*1600
                   : (j < 256) ? fc2w + (j-128)*1600
                               : fc3w + (j-256)*1600;
  for (int k = threadIdx.x; k < 1600; k += 256)
    g_Wc[j*1600 + k] = f2bfs(src[k]);
}

// ---------------- Kernel 1: LSTM via MFMA (R18 verified best) ----------------
// 512 blocks x 512 threads (8 waves), 64 samples/block, VGPR=128(+64 AGPR) ->
// 1 block/CU resident (2 waves/SIMD), the register-file optimum (R14 model;
// 11 occupancy probes all regressed). ALL weights in per-wave register
// B-fragments; LDS = only the h exchange, double-buffered (32KB); single
// lgkm-only barrier per timestep; DPP lane^1 exchange (R18: -12us vs shfl).
__global__ __launch_bounds__(512, 1) void lstm2_mfma_kernel(
    const float* __restrict__ x,
    const float* __restrict__ wih0, const float* __restrict__ whh0,
    const float* __restrict__ bih0, const float* __restrict__ bhh0,
    const float* __restrict__ wih1, const float* __restrict__ whh1,
    const float* __restrict__ bih1, const float* __restrict__ bhh1,
    short* __restrict__ flat)                 // [BATCH][1600] bf16
{
  __shared__ short Abuf[4*64*64];   // 32 KiB: h0[0],h0[1],h1[0],h1[1]; [64s][64u] each
  char* const Ab = (char*)Abuf;     // region r at byte r*8192; row=128B, XOR-swizzled

  const int tid  = threadIdx.x;
  const int lane = tid & 63;
  const int wv   = tid >> 6;
  const int w4   = wv & 3;          // unit group
  const int wg   = wv >> 2;         // sample half
  const int lrow = lane & 15;
  const int lk   = lane >> 4;
  const int sw   = (lrow & 7) << 4;
  const int sb   = blockIdx.x * 64;
  const int u    = w4*16 + lrow;

  // ---- zero h0buf[1], h1buf[1] (read at t=0) ----
  {
    s16x8 z = {0,0,0,0,0,0,0,0};
    int idx = tid * 32;
    char* pz = Ab + ((idx < 8192) ? 8192 + idx : 16384 + idx);
    *(s16x8*)pz = z; *(s16x8*)(pz + 16) = z;
  }

  // ---- ALL weights as register B-fragments ----
  s16x8 W1f[4][4], B0x[4], B0h[4][2];
  #pragma unroll
  for (int n = 0; n < 4; n++){
    const int g = n*64 + u;                       // gate n, unit u
    #pragma unroll
    for (int kt = 0; kt < 4; kt++){
      const float* src = (kt < 2 ? wih1 + g*64 + kt*32 : whh1 + g*64 + (kt-2)*32) + lk*8;
      W1f[n][kt] = pack8(*(const float4*)src, *(const float4*)(src+4));
    }
    if (lk < 2){
      const float* src = wih0 + g*16 + lk*8;
      B0x[n] = pack8(*(const float4*)src, *(const float4*)(src+4));
    } else {
      s16x8 z = {0,0,0,0,0,0,0,0}; B0x[n] = z;
    }
    #pragma unroll
    for (int kt = 0; kt < 2; kt++){
      const float* src = whh0 + g*64 + kt*32 + lk*8;
      B0h[n][kt] = pack8(*(const float4*)src, *(const float4*)(src+4));
    }
  }

  // ---- biases (i,f,g,o for unit u) ----
  float b0v[4], b1v[4];
  #pragma unroll
  for (int n = 0; n < 4; n++){
    b0v[n] = bih0[n*64+u] + bhh0[n*64+u];
    b1v[n] = bih1[n*64+u] + bhh1[n*64+u];
  }

  // ---- x fragment pointers + t=0 prefetch ----
  const float* xbase[2];
  #pragma unroll
  for (int m = 0; m < 2; m++)
    xbase[m] = x + (size_t)(sb + wg*32 + m*16 + lrow)*(TT*16) + (lk&1)*8;
  s16x8 xf[2];
  #pragma unroll
  for (int m = 0; m < 2; m++)
    xf[m] = pack8(*(const float4*)(xbase[m]), *(const float4*)(xbase[m] + 4));

  float c0[2][4], c1[2][4];
  #pragma unroll
  for (int m = 0; m < 2; m++)
    #pragma unroll
    for (int r = 0; r < 4; r++){ c0[m][r] = 0.f; c1[m][r] = 0.f; }

  __syncthreads();   // one-time full barrier after staging

  #pragma unroll 1
  for (int t = 0; t < TT; t++){
    const int p  = t & 1;
    const int pn = p ^ 1;
    // ======== layer 0: x-tile (regs) + 2 h0-tiles from h0buf[pn] ========
    f32x4 acc[2][4];
    #pragma unroll
    for (int m = 0; m < 2; m++)
      #pragma unroll
      for (int n = 0; n < 4; n++){ f32x4 iv = {b0v[n],b0v[n],b0v[n],b0v[n]}; acc[m][n] = iv; }
    #pragma unroll
    for (int m = 0; m < 2; m++)
      #pragma unroll
      for (int n = 0; n < 4; n++)
        acc[m][n] = __builtin_amdgcn_mfma_f32_16x16x32_bf16(xf[m], B0x[n], acc[m][n], 0, 0, 0);
    #pragma unroll
    for (int kt = 0; kt < 2; kt++){
      s16x8 a[2];
      #pragma unroll
      for (int m = 0; m < 2; m++){
        int row = wg*32 + m*16 + lrow;
        a[m] = *(const s16x8*)(Ab + pn*8192 + row*128 + ((kt*64 + lk*16) ^ sw));
      }
      #pragma unroll
      for (int m = 0; m < 2; m++)
        #pragma unroll
        for (int n = 0; n < 4; n++)
          acc[m][n] = __builtin_amdgcn_mfma_f32_16x16x32_bf16(a[m], B0h[n][kt], acc[m][n], 0, 0, 0);
    }
    short hb[2][4];
    #pragma unroll
    for (int m = 0; m < 2; m++)
      #pragma unroll
      for (int r = 0; r < 4; r++){
        float iv = sigm(acc[m][0][r]);
        float fv = sigm(acc[m][1][r]);
        float gv = tanh_(acc[m][2][r]);
        float ov = sigm(acc[m][3][r]);
        float c  = fmaf(fv, c0[m][r], iv*gv); c0[m][r] = c;
        hb[m][r] = f2bfs(ov * tanh_(c));
      }
    // write h0[t] to h0buf[p] (disjoint from h0buf[pn] being read)
    #pragma unroll
    for (int m = 0; m < 2; m++)
      #pragma unroll
      for (int r = 0; r < 4; r++){
        int mine = (int)(uint16_t)hb[m][r];
        int part = dpp_swap1(mine);
        if ((lane & 1) == 0){
          int s_ = wg*32 + m*16 + lk*4 + r;
          uint32_t pk = (uint32_t)mine | ((uint32_t)part << 16);
          *(uint32_t*)(Ab + p*8192 + s_*128 + ((u*2) ^ ((s_&7)<<4))) = pk;
        }
      }
    barrier_lds_only();   // S1 (the ONLY barrier): h0[t] and h1[t-1] visible

    // ======== layer 1: reads h0buf[p] (kt 0,1) + h1buf[pn] (kt 2,3) ========
    // Hazards without an end-of-phase barrier (double-buffered regions):
    //   h1[t] write -> read L1[t+1]: next phase's S1 between.     RAW ok
    //   h0buf[pn] read (pre-S1_t) -> rewritten after S1_{t+1}.    WAR ok
    //   h1buf[pn] read (post-S1_t) -> rewritten after S1_{t+1}.   WAR ok
    s16x8 xfn[2];
    if (t + 1 < TT){
      #pragma unroll
      for (int m = 0; m < 2; m++)
        xfn[m] = pack8(*(const float4*)(xbase[m] + (t+1)*16),
                       *(const float4*)(xbase[m] + (t+1)*16 + 4));
    }
    #pragma unroll
    for (int m = 0; m < 2; m++)
      #pragma unroll
      for (int n = 0; n < 4; n++){ f32x4 iv = {b1v[n],b1v[n],b1v[n],b1v[n]}; acc[m][n] = iv; }
    #pragma unroll
    for (int kt = 0; kt < 4; kt++){
      const int reg = (kt < 2) ? p*8192 : 16384 + pn*8192;
      const int ko  = (kt & 1) * 64;
      s16x8 a[2];
      #pragma unroll
      for (int m = 0; m < 2; m++){
        int row = wg*32 + m*16 + lrow;
        a[m] = *(const s16x8*)(Ab + reg + row*128 + ((ko + lk*16) ^ sw));
      }
      #pragma unroll
      for (int m = 0; m < 2; m++)
        #pragma unroll
        for (int n = 0; n < 4; n++)
          acc[m][n] = __builtin_amdgcn_mfma_f32_16x16x32_bf16(a[m], W1f[n][kt], acc[m][n], 0, 0, 0);
    }
    #pragma unroll
    for (int m = 0; m < 2; m++)
      #pragma unroll
      for (int r = 0; r < 4; r++){
        float iv = sigm(acc[m][0][r]);
        float fv = sigm(acc[m][1][r]);
        float gv = tanh_(acc[m][2][r]);
        float ov = sigm(acc[m][3][r]);
        float c  = fmaf(fv, c1[m][r], iv*gv); c1[m][r] = c;
        hb[m][r] = f2bfs(ov * tanh_(c));
      }
    // write h1[t] to h1buf[p] + flat. Visible to L1[t+1] via next phase's S1.
    // flat stores are fire-and-forget; kernel completion fences them for fc.
    #pragma unroll
    for (int m = 0; m < 2; m++)
      #pragma unroll
      for (int r = 0; r < 4; r++){
        int mine = (int)(uint16_t)hb[m][r];
        int part = dpp_swap1(mine);
        if ((lane & 1) == 0){
          int s_ = wg*32 + m*16 + lk*4 + r;
          uint32_t pk = (uint32_t)mine | ((uint32_t)part << 16);
          *(uint32_t*)(Ab + 16384 + p*8192 + s_*128 + ((u*2) ^ ((s_&7)<<4))) = pk;
          *(uint32_t*)(flat + (size_t)(sb+s_)*1600 + t*64 + u) = pk;
        }
      }
    #pragma unroll
    for (int m = 0; m < 2; m++) xf[m] = xfn[m];
    // no end-of-phase barrier: next phase's S1 covers all hazards (see above)
  }
}

// ---------------- Kernel 2: FC GEMM + MFMA heads (R11 + DPP exchange) --------
// 512 blocks x 256 threads (4 waves, 64 samples). R bf16 in swizzled LDS
// (48KB); heads via 3 padded-N MFMA tiles. CHANGE vs R18: the 96 per-thread
// __shfl_xor(v,1) in the R-write phase -> mov_dpp (R18 lstm evidence: shfl
// lowers via the LDS pipe and contends with the Rs ds_writes).
__global__ __launch_bounds__(256,1) void fc_mfma_kernel(
    const short* __restrict__ flat,
    const float* __restrict__ fc1b, const float* __restrict__ fc2b, const float* __restrict__ fc3b,
    const float* __restrict__ l1w,  const float* __restrict__ l1b,
    const float* __restrict__ l2w,  const float* __restrict__ l2b,
    const float* __restrict__ l3w,  const float* __restrict__ l3b,
    float* __restrict__ out)
{
  __shared__ short Rs[64*384];    // 48KB bf16, row=768B, XOR-swizzled
  char* const Rb = (char*)Rs;
  const int tid  = threadIdx.x;
  const int lane = tid & 63;
  const int wv   = tid >> 6;      // wave owns fc cols [96w, 96w+96)
  const int lrow = lane & 15;
  const int lk   = lane >> 4;
  const int sb   = blockIdx.x * 64;

  f32x4 acc[4][6];
  #pragma unroll
  for (int n = 0; n < 6; n++){
    int j = wv*96 + n*16 + lrow;
    float bv = (j < 128) ? fc1b[j] : (j < 256) ? fc2b[j-128] : fc3b[j-256];
    #pragma unroll
    for (int m = 0; m < 4; m++){ f32x4 iv = {bv,bv,bv,bv}; acc[m][n] = iv; }
  }

  const char* Abase = (const char*)(flat + (size_t)sb*1600);
  const char* Bbase = (const char*)g_Wc;
  #pragma unroll 1
  for (int kc = 0; kc < 50; kc++){
    s16x8 a[4], b[6];
    #pragma unroll
    for (int m = 0; m < 4; m++)
      a[m] = *(const s16x8*)(Abase + (size_t)(m*16+lrow)*3200 + kc*64 + lk*16);
    #pragma unroll
    for (int n = 0; n < 6; n++)
      b[n] = *(const s16x8*)(Bbase + (size_t)(wv*96+n*16+lrow)*3200 + kc*64 + lk*16);
    #pragma unroll
    for (int m = 0; m < 4; m++)
      #pragma unroll
      for (int n = 0; n < 6; n++)
        acc[m][n] = __builtin_amdgcn_mfma_f32_16x16x32_bf16(a[m], b[n], acc[m][n], 0, 0, 0);
  }

  // ---- ReLU + write R as bf16 pairs (lane^1 exchange via DPP) ----
  #pragma unroll
  for (int m = 0; m < 4; m++)
    #pragma unroll
    for (int n = 0; n < 6; n++)
      #pragma unroll
      for (int r = 0; r < 4; r++){
        float v  = fmaxf(acc[m][n][r], 0.f);
        float vp = dpp_swap1f(v);
        uint32_t pk = cvt_pk_bf16(v, vp);
        if ((lane & 1) == 0){
          int s_ = m*16 + lk*4 + r;
          int fc = wv*96 + n*16 + lrow;
          *(uint32_t*)(Rb + s_*768 + ((fc*2) ^ ((s_&7)<<4))) = pk;
        }
      }
  __syncthreads();

  // ---- heads as 3 padded-N MFMA tiles (K=128 each) ----
  const float* Lw[3] = {l1w, l2w, l3w};
  const int   odim[3] = {5, 4, 8};
  s16x8 Bh[3][4];
  #pragma unroll
  for (int q = 0; q < 3; q++){
    #pragma unroll
    for (int kt = 0; kt < 4; kt++){
      if (lrow < odim[q]){
        const float* src = Lw[q] + lrow*128 + kt*32 + lk*8;
        Bh[q][kt] = pack8(*(const float4*)src, *(const float4*)(src+4));
      } else {
        s16x8 z = {0,0,0,0,0,0,0,0}; Bh[q][kt] = z;
      }
    }
  }
  f32x4 acc2[4][3];
  {
    float bv0 = (lrow < 5) ? l1b[lrow] : 0.f;
    float bv1 = (lrow < 4) ? l2b[lrow] : 0.f;
    float bv2 = (lrow < 8) ? l3b[lrow] : 0.f;
    #pragma unroll
    for (int m = 0; m < 4; m++){
      f32x4 i0 = {bv0,bv0,bv0,bv0}; acc2[m][0] = i0;
      f32x4 i1 = {bv1,bv1,bv1,bv1}; acc2[m][1] = i1;
      f32x4 i2 = {bv2,bv2,bv2,bv2}; acc2[m][2] = i2;
    }
  }
  #pragma unroll
  for (int q = 0; q < 3; q++){
    #pragma unroll
    for (int kt = 0; kt < 4; kt++){
      s16x8 av[4];
      #pragma unroll
      for (int m = 0; m < 4; m++){
        int row = m*16 + lrow;
        av[m] = *(const s16x8*)(Rb + row*768 + ((q*256 + kt*64 + lk*16) ^ ((row&7)<<4)));
      }
      #pragma unroll
      for (int m = 0; m < 4; m++)
        acc2[m][q] = __builtin_amdgcn_mfma_f32_16x16x32_bf16(av[m], Bh[q][kt], acc2[m][q], 0, 0, 0);
    }
  }
  #pragma unroll
  for (int m = 0; m < 4; m++)
    #pragma unroll
    for (int r = 0; r < 4; r++){
      int smp = sb + m*16 + lk*4 + r;
      if (lrow < 5) out[(size_t)smp*5 + lrow] = acc2[m][0][r];
      if (lrow < 4) out[(size_t)BATCH*5 + (size_t)smp*4 + lrow] = acc2[m][1][r];
      if (lrow < 8) out[(size_t)BATCH*9 + (size_t)smp*8 + lrow] = acc2[m][2][r];
    }
}

extern "C" void kernel_launch(void* const* d_in, const int* in_sizes, int n_in,
                              void* d_out, int out_size, void* d_ws, size_t ws_size,
                              hipStream_t stream)
{
  const float* x    = (const float*)d_in[0];
  const float* wih0 = (const float*)d_in[1];
  const float* whh0 = (const float*)d_in[2];
  const float* bih0 = (const float*)d_in[3];
  const float* bhh0 = (const float*)d_in[4];
  const float* wih1 = (const float*)d_in[5];
  const float* whh1 = (const float*)d_in[6];
  const float* bih1 = (const float*)d_in[7];
  const float* bhh1 = (const float*)d_in[8];
  const float* fc1w = (const float*)d_in[9];
  const float* fc1b = (const float*)d_in[10];
  const float* fc2w = (const float*)d_in[11];
  const float* fc2b = (const float*)d_in[12];
  const float* fc3w = (const float*)d_in[13];
  const float* fc3b = (const float*)d_in[14];
  const float* l1w  = (const float*)d_in[15];
  const float* l1b  = (const float*)d_in[16];
  const float* l2w  = (const float*)d_in[17];
  const float* l2b  = (const float*)d_in[18];
  const float* l3w  = (const float*)d_in[19];
  const float* l3b  = (const float*)d_in[20];

  float* out  = (float*)d_out;
  short* flat = (short*)d_ws;
  if (ws_size < (size_t)BATCH*1600*2) return;

  conv_wc_kernel<<<dim3(384), dim3(256), 0, stream>>>(fc1w, fc2w, fc3w);

  lstm2_mfma_kernel<<<dim3(BATCH/64), dim3(512), 0, stream>>>(
      x, wih0, whh0, bih0, bhh0, wih1, whh1, bih1, bhh1, flat);

  fc_mfma_kernel<<<dim3(BATCH/64), dim3(256), 0, stream>>>(
      flat, fc1b, fc2b, fc3b, l1w, l1b, l2w, l2b, l3w, l3b, out);
}